// Round 6
// baseline (417.114 us; speedup 1.0000x reference)
//
#include <hip/hip_runtime.h>
#include <stdint.h>

typedef __attribute__((ext_vector_type(8))) short short8;
typedef __attribute__((ext_vector_type(4))) float floatx4;

#define DEV static __device__ __forceinline__

constexpr int Bb = 32, Pp = 577, Dd = 768, Hh = 12;
constexpr int M_VALID = Bb * Pp;      // 18464
constexpr int M_PAD   = 18560;        // 145 * 128 (storage rows of C1/Xb)
constexpr int PKV     = 640;          // padded kv length (10 * 64)
constexpr float SCALE_LOG2E = 0.10206207261596577f * 1.4426950408889634f;

DEV ushort f2b(float f) {
  union { float f; uint32_t u; } c; c.f = f;
  uint32_t u = c.u + 0x7fffu + ((c.u >> 16) & 1u);
  return (ushort)(u >> 16);
}

// ---------------- fp32 -> bf16 conversion with zero padding ----------------
__global__ void cvt_pad(const float* __restrict__ src, ushort* __restrict__ dst,
                        int n_valid4, int n_total4) {
  const float4* s4 = (const float4*)src;
  for (int i = blockIdx.x * blockDim.x + threadIdx.x; i < n_total4;
       i += gridDim.x * blockDim.x) {
    float4 v = make_float4(0.f, 0.f, 0.f, 0.f);
    if (i < n_valid4) v = s4[i];
    ushort4 o;
    o.x = f2b(v.x); o.y = f2b(v.y); o.z = f2b(v.z); o.w = f2b(v.w);
    ((ushort4*)dst)[i] = o;
  }
}

// ---------------- bf16 GEMM: C[M,N] = A[M,K] * B[N,K]^T + bias -------------
// 256x128 tile, BK=32, 4 waves (2x2) each owning 128x64 (8x4 fragments),
// CHUNK-MAJOR LDS (conflict-free ds_read_b128), 3-deep pipeline with counted
// vmcnt, global_load_lds width 16, bijective chunked XCD swizzle (m204).
// LDS per buffer: A 256x32 chunk-major [4][256][8], B 128x32 [4][128][8].
#define STAGE(bi, kk)                                                          \
  do {                                                                         \
    _Pragma("unroll")                                                          \
    for (int c_ = 0; c_ < 4; ++c_)                                             \
      __builtin_amdgcn_global_load_lds(                                        \
          (const __attribute__((address_space(1))) void*)(gA + c_ * 8 + (kk)), \
          (__attribute__((address_space(3))) void*)(As + (bi)*8192 + c_*2048 + tid*8), \
          16, 0, 0);                                                           \
    _Pragma("unroll")                                                          \
    for (int c_ = 0; c_ < 2; ++c_)                                             \
      __builtin_amdgcn_global_load_lds(                                        \
          (const __attribute__((address_space(1))) void*)(gB + c_ * 16 + (kk)),\
          (__attribute__((address_space(3))) void*)(Bs + (bi)*4096 + c_*2048 + tid*8), \
          16, 0, 0);                                                           \
  } while (0)

template<bool C_F32>
__global__ __launch_bounds__(256, 2) void gemm_bt(
    const ushort* __restrict__ A, int lda,
    const ushort* __restrict__ Bw,
    const float* __restrict__ bias, void* __restrict__ Cout,
    int N, int K, int m_valid, int nt_n)
{
  __shared__ ushort As[3 * 8192];     // 3 x [4 chunks][256 rows][8]
  __shared__ ushort Bs[3 * 4096];     // 3 x [4 chunks][128 rows][8]
  const int tid = threadIdx.x;
  const int lane = tid & 63;
  const int w = tid >> 6;
  const int wr = w >> 1, wc = w & 1;  // wave owns rows wr*128.., cols wc*64..
  const int llo = lane & 15, lhi = lane >> 4;

  // bijective chunked XCD swizzle (m204)
  const int nwg = gridDim.x;
  const int L = blockIdx.x;
  const int q = nwg >> 3, r = nwg & 7;
  const int xcd = L & 7, pos = L >> 3;
  const int wgid = (xcd < r ? xcd * (q + 1) : r * (q + 1) + (xcd - r) * q) + pos;
  const int m0 = (wgid / nt_n) * 256, n0 = (wgid % nt_n) * 128;

  floatx4 acc[8][4];
#pragma unroll
  for (int i = 0; i < 8; ++i)
#pragma unroll
    for (int j = 0; j < 4; ++j) acc[i][j] = floatx4{0.f, 0.f, 0.f, 0.f};

  // staging sources: A thread tid -> row tid (chunk per instruction);
  // B thread tid -> row tid&127, chunk (tid>>7) + 2*instr
  const ushort* gA = A + ((size_t)m0 + tid) * lda;
  const ushort* gB = Bw + (size_t)(n0 + (tid & 127)) * K + (tid >> 7) * 8;

  STAGE(0, 0);
  STAGE(1, 32);
  int cur = 0;
  for (int kk = 0; kk < K; kk += 32) {
    if (kk + 64 < K) {
      int b2 = cur + 2; if (b2 >= 3) b2 -= 3;
      STAGE(b2, kk + 64);                         // keep 2 tiles in flight
      asm volatile("s_waitcnt vmcnt(12)" ::: "memory");  // tile kk landed
    } else if (kk + 32 < K) {
      asm volatile("s_waitcnt vmcnt(6)" ::: "memory");
    } else {
      asm volatile("s_waitcnt vmcnt(0)" ::: "memory");
    }
    __builtin_amdgcn_s_barrier();                 // all slices of buf[cur] landed
    __builtin_amdgcn_sched_barrier(0);

    const ushort* Ab = As + cur * 8192;
    const ushort* Bbp = Bs + cur * 4096;
    short8 af[8], bfr[4];
#pragma unroll
    for (int j = 0; j < 4; ++j)
      bfr[j] = *(const short8*)(Bbp + lhi * 1024 + (wc * 64 + j * 16 + llo) * 8);
#pragma unroll
    for (int i = 0; i < 8; ++i)
      af[i] = *(const short8*)(Ab + lhi * 2048 + (wr * 128 + i * 16 + llo) * 8);
#pragma unroll
    for (int i = 0; i < 8; ++i)
#pragma unroll
      for (int j = 0; j < 4; ++j)
        acc[i][j] = __builtin_amdgcn_mfma_f32_16x16x32_bf16(af[i], bfr[j], acc[i][j], 0, 0, 0);

    __builtin_amdgcn_sched_barrier(0);            // keep ds_reads in this phase
    __builtin_amdgcn_s_barrier();                 // reads done before buf reuse
    cur += 1; if (cur >= 3) cur -= 3;
  }

  float bv[4];
#pragma unroll
  for (int j = 0; j < 4; ++j) bv[j] = bias[n0 + wc * 64 + j * 16 + llo];

#pragma unroll
  for (int i = 0; i < 8; ++i) {
#pragma unroll
    for (int r2 = 0; r2 < 4; ++r2) {
      const int row = m0 + wr * 128 + i * 16 + lhi * 4 + r2;
      if (row >= m_valid) continue;
      const size_t rb = (size_t)row * N + n0 + wc * 64;
#pragma unroll
      for (int j = 0; j < 4; ++j) {
        float v = acc[i][j][r2] + bv[j];
        if (C_F32) ((float*)Cout)[rb + j * 16 + llo] = v;
        else       ((ushort*)Cout)[rb + j * 16 + llo] = f2b(v);
      }
    }
  }
}

// ---------------- V transpose pre-pass -------------------------------------
// C1 v-cols [b*Pp+p][h*64+ss]  ->  Vt[(b*Hh+h)*64+ss][p]  (p padded to 640, 0)
__global__ __launch_bounds__(256) void vtrans(const ushort* __restrict__ C1,
                                              ushort* __restrict__ Vt) {
  const int pt = blockIdx.x, h = blockIdx.y, b = blockIdx.z;
  __shared__ ushort Ts[64][72];
  const int t = threadIdx.x;
  const int rl = t >> 2, c16 = (t & 3) * 16;
  const int p = pt * 64 + rl;
  short8 a0 = {0,0,0,0,0,0,0,0}, a1 = {0,0,0,0,0,0,0,0};
  if (p < Pp) {
    const ushort* s = C1 + (size_t)(b * Pp + p) * 2304 + h * 64 + c16;
    a0 = *(const short8*)s;
    a1 = *(const short8*)(s + 8);
  }
  *(short8*)&Ts[rl][c16] = a0;
  *(short8*)&Ts[rl][c16 + 8] = a1;
  __syncthreads();
  const int ss = t >> 2, pc16 = (t & 3) * 16;
  short8 o0, o1;
#pragma unroll
  for (int i = 0; i < 8; ++i) {
    o0[i] = (short)Ts[pc16 + i][ss];
    o1[i] = (short)Ts[pc16 + 8 + i][ss];
  }
  ushort* d = Vt + ((size_t)(b * Hh + h) * 64 + ss) * PKV + pt * 64 + pc16;
  *(short8*)d = o0;
  *(short8*)(d + 8) = o1;
}

// ---------------- flash attention (no-max, deferred-sum) -------------------
// 128 q-rows/block (8 waves x 16 rows), T14 async-STAGE split.
// Q,K from C1 (q at +768, k at +1536); V from Vt (transposed, [bh*64+ss][p]).
// O written into C1 v-cols (stride 2304).
__global__ __launch_bounds__(512) void attn_fwd(
    ushort* C1, const ushort* __restrict__ Vt)
{
  const int qt = blockIdx.x, h = blockIdx.y, b = blockIdx.z;
  const int tid = threadIdx.x;
  const int lane = tid & 63, w = tid >> 6;          // w: 0..7
  const int llo = lane & 15, lhi = lane >> 4;

  __shared__ ushort Ks[64][72];      // K rows (kv-local x d), padded
  __shared__ ushort Vs[64][72];      // V^T rows (ss x kv-local), padded
  __shared__ ushort Ps[8][16][72];   // per-wave P tile (wave-private)

  const int q0 = qt * 128;
  const int qrow = q0 + w * 16 + llo;   // may exceed 576: finite, never stored
  const size_t qoff = (size_t)(b * Pp + qrow) * 2304 + 768 + h * 64;
  const short8 qf0 = *(const short8*)(C1 + qoff + lhi * 8);
  const short8 qf1 = *(const short8*)(C1 + qoff + 32 + lhi * 8);

  float ls[4] = {0.f, 0.f, 0.f, 0.f};
  floatx4 acc_o[4];
#pragma unroll
  for (int st = 0; st < 4; ++st) acc_o[st] = floatx4{0.f, 0.f, 0.f, 0.f};

  const int srow = tid >> 3;          // 0..63
  const int sc8 = (tid & 7) * 8;
  const ushort* kbase = C1 + (size_t)(b * Pp + srow) * 2304 + 1536 + h * 64 + sc8;
  const ushort* vbase = Vt + ((size_t)(b * Hh + h) * 64 + srow) * PKV + sc8;

  // T14 prologue: issue tile-0 loads
  short8 kc = *(const short8*)(kbase);
  short8 vc = *(const short8*)(vbase);

  for (int t = 0; t < 10; ++t) {
    __syncthreads();                  // prev iter LDS reads done
    *(short8*)&Ks[srow][sc8] = kc;
    *(short8*)&Vs[srow][sc8] = vc;
    if (t < 9) {                      // issue next tile loads; land during compute
      kc = *(const short8*)(kbase + (size_t)(t + 1) * 64 * 2304);
      vc = *(const short8*)(vbase + (t + 1) * 64);
    }
    __syncthreads();

    // S = Q K^T ; P = exp2(S*scale*log2e) (no max-sub: |S*scale| <~ 2)
    float pv[4][4];                   // [ntile][r]
#pragma unroll
    for (int ntl = 0; ntl < 4; ++ntl) {
      floatx4 acc = floatx4{0.f, 0.f, 0.f, 0.f};
      const short8 bf0 = *(const short8*)&Ks[ntl * 16 + llo][lhi * 8];
      const short8 bf1 = *(const short8*)&Ks[ntl * 16 + llo][32 + lhi * 8];
      acc = __builtin_amdgcn_mfma_f32_16x16x32_bf16(qf0, bf0, acc, 0, 0, 0);
      acc = __builtin_amdgcn_mfma_f32_16x16x32_bf16(qf1, bf1, acc, 0, 0, 0);
      const bool valid = (t * 64 + ntl * 16 + llo) < Pp;
#pragma unroll
      for (int r = 0; r < 4; ++r) {
        const float p = valid ? exp2f(acc[r] * SCALE_LOG2E) : 0.f;
        pv[ntl][r] = p;
        ls[r] += p;
      }
    }

    // P -> LDS (bf16), wave-private: no barrier needed
#pragma unroll
    for (int r = 0; r < 4; ++r)
#pragma unroll
      for (int ntl = 0; ntl < 4; ++ntl)
        Ps[w][lhi * 4 + r][ntl * 16 + llo] = f2b(pv[ntl][r]);

    // O += P V
    const short8 pa0 = *(const short8*)&Ps[w][llo][lhi * 8];
    const short8 pa1 = *(const short8*)&Ps[w][llo][32 + lhi * 8];
#pragma unroll
    for (int st = 0; st < 4; ++st) {
      const short8 vb0 = *(const short8*)&Vs[st * 16 + llo][lhi * 8];
      const short8 vb1 = *(const short8*)&Vs[st * 16 + llo][32 + lhi * 8];
      acc_o[st] = __builtin_amdgcn_mfma_f32_16x16x32_bf16(pa0, vb0, acc_o[st], 0, 0, 0);
      acc_o[st] = __builtin_amdgcn_mfma_f32_16x16x32_bf16(pa1, vb1, acc_o[st], 0, 0, 0);
    }
  }

  // single deferred sum-reduce across the 16 lanes holding each row
#pragma unroll
  for (int r = 0; r < 4; ++r) {
#pragma unroll
    for (int off = 1; off < 16; off <<= 1) ls[r] += __shfl_xor(ls[r], off, 64);
  }

#pragma unroll
  for (int r = 0; r < 4; ++r) {
    const int p = q0 + w * 16 + lhi * 4 + r;
    if (p < Pp) {
      const float inv = 1.f / ls[r];
      const size_t ob = (size_t)(b * Pp + p) * 2304 + h * 64;  // O into C1 v-cols
#pragma unroll
      for (int st = 0; st < 4; ++st)
        C1[ob + st * 16 + llo] = f2b(acc_o[st][r] * inv);
    }
  }
}

// ---------------- launch ----------------------------------------------------
extern "C" void kernel_launch(void* const* d_in, const int* in_sizes, int n_in,
                              void* d_out, int out_size, void* d_ws, size_t ws_size,
                              hipStream_t stream) {
  const float* x     = (const float*)d_in[0];
  const float* qkv_w = (const float*)d_in[1];
  const float* qkv_b = (const float*)d_in[2];
  const float* out_w = (const float*)d_in[3];
  const float* out_b = (const float*)d_in[4];
  float* out = (float*)d_out;

  char* ws = (char*)d_ws;
  // layout (118.75 MB total). Order chosen so BM=256 OOB tail reads (rows
  // M_PAD..18687) of Xb and C1b land in the NEXT allocated buffer:
  //   Xb   [0, 28.51MB)            x bf16 (dead after QKV GEMM)
  //   W1b  [28.51, 32.05)          qkv_w bf16 (dead after QKV GEMM)
  //   C1b  [32.05, 117.57)         qkv out; O later overwrites its v-cols
  //   W3b  [117.57, 118.75)        out_w bf16 (live until final GEMM)
  //   Vtb  [0, 31.46)              overlays Xb+W1b (written after both die)
  ushort* Xb  = (ushort*)(ws);
  ushort* W1b = (ushort*)(ws + 28508160);
  ushort* C1b = (ushort*)(ws + 32047104);
  ushort* W3b = (ushort*)(ws + 117571584);
  ushort* Vtb = (ushort*)(ws);

  cvt_pad<<<2048, 256, 0, stream>>>(x, Xb, M_VALID * 768 / 4, M_PAD * 768 / 4);
  cvt_pad<<<1024, 256, 0, stream>>>(qkv_w, W1b, 2304 * 768 / 4, 2304 * 768 / 4);
  cvt_pad<<<512, 256, 0, stream>>>(out_w, W3b, 768 * 768 / 4, 768 * 768 / 4);

  // M-tiles of 256: ceil(18560/256)=73 (tail rows guarded by m_valid)
  gemm_bt<false><<<dim3(73 * 18), 256, 0, stream>>>(Xb, 768, W1b, qkv_b,
                                                    (void*)C1b, 2304, 768, M_PAD, 18);
  vtrans<<<dim3(10, 12, 32), 256, 0, stream>>>(C1b, Vtb);
  attn_fwd<<<dim3(5, 12, 32), 512, 0, stream>>>(C1b, Vtb);
  gemm_bt<true><<<dim3(73 * 6), 256, 0, stream>>>(C1b, 2304, W3b, out_b,
                                                  (void*)out, 768, 768, M_VALID, 6);
}

// Round 7
// 355.898 us; speedup vs baseline: 1.1720x; 1.1720x over previous
//
#include <hip/hip_runtime.h>
#include <stdint.h>

typedef __attribute__((ext_vector_type(8))) short short8;
typedef __attribute__((ext_vector_type(4))) float floatx4;

#define DEV static __device__ __forceinline__

constexpr int Bb = 32, Pp = 577, Dd = 768, Hh = 12;
constexpr int M_VALID = Bb * Pp;      // 18464
constexpr int M_PAD   = 18560;        // 145 * 128 (storage rows of C1/Xb)
constexpr int PKV     = 640;          // padded kv length (10 * 64)
constexpr float SCALE_LOG2E = 0.10206207261596577f * 1.4426950408889634f;

DEV ushort f2b(float f) {
  union { float f; uint32_t u; } c; c.f = f;
  uint32_t u = c.u + 0x7fffu + ((c.u >> 16) & 1u);
  return (ushort)(u >> 16);
}

// ---------------- fp32 -> bf16 conversion with zero padding ----------------
__global__ void cvt_pad(const float* __restrict__ src, ushort* __restrict__ dst,
                        int n_valid4, int n_total4) {
  const float4* s4 = (const float4*)src;
  for (int i = blockIdx.x * blockDim.x + threadIdx.x; i < n_total4;
       i += gridDim.x * blockDim.x) {
    float4 v = make_float4(0.f, 0.f, 0.f, 0.f);
    if (i < n_valid4) v = s4[i];
    ushort4 o;
    o.x = f2b(v.x); o.y = f2b(v.y); o.z = f2b(v.z); o.w = f2b(v.w);
    ((ushort4*)dst)[i] = o;
  }
}

// ---------------- bf16 GEMM: C[M,N] = A[M,K] * B[N,K]^T + bias -------------
// 128x128 tile, BK=32, 4 waves (2x2), global_load_lds width 16, 3-deep
// pipeline with counted vmcnt, bijective chunked XCD swizzle (m204).
// LDS granule-XOR swizzle (rule #21c): slot (row, c) holds global chunk
// c ^ ((row>>1)&3); staging pre-swizzles the GLOBAL column (coalescing kept:
// each 4-lane cluster still covers one contiguous 64B row-slab), reads XOR
// per-lane-constant. -> every 8-lane group hits all 8 LDS 16B granules.
#define STAGE(bi, kk)                                                          \
  do {                                                                         \
    __builtin_amdgcn_global_load_lds(                                          \
        (const __attribute__((address_space(1))) void*)(gA0 + (kk)),           \
        (__attribute__((address_space(3))) void*)(As + (bi)*4096 + tid * 8),   \
        16, 0, 0);                                                             \
    __builtin_amdgcn_global_load_lds(                                          \
        (const __attribute__((address_space(1))) void*)(gA1 + (kk)),           \
        (__attribute__((address_space(3))) void*)(As + (bi)*4096 + 2048 + tid * 8), \
        16, 0, 0);                                                             \
    __builtin_amdgcn_global_load_lds(                                          \
        (const __attribute__((address_space(1))) void*)(gB0 + (kk)),           \
        (__attribute__((address_space(3))) void*)(Bs + (bi)*4096 + tid * 8),   \
        16, 0, 0);                                                             \
    __builtin_amdgcn_global_load_lds(                                          \
        (const __attribute__((address_space(1))) void*)(gB1 + (kk)),           \
        (__attribute__((address_space(3))) void*)(Bs + (bi)*4096 + 2048 + tid * 8), \
        16, 0, 0);                                                             \
  } while (0)

template<bool C_F32>
__global__ __launch_bounds__(256) void gemm_bt(
    const ushort* __restrict__ A, int lda,
    const ushort* __restrict__ Bw,
    const float* __restrict__ bias, void* __restrict__ Cout,
    int N, int K, int m_valid, int nt_n)
{
  __shared__ ushort As[3 * 128 * 32];
  __shared__ ushort Bs[3 * 128 * 32];
  const int tid = threadIdx.x;
  const int lane = tid & 63;
  const int w = tid >> 6;
  const int wr = w >> 1, wc = w & 1;
  const int llo = lane & 15, lhi = lane >> 4;

  // bijective chunked XCD swizzle (m204)
  const int nwg = gridDim.x;
  const int L = blockIdx.x;
  const int q = nwg >> 3, r = nwg & 7;
  const int xcd = L & 7, pos = L >> 3;
  const int wgid = (xcd < r ? xcd * (q + 1) : r * (q + 1) + (xcd - r) * q) + pos;
  const int m0 = (wgid / nt_n) * 128, n0 = (wgid % nt_n) * 128;

  floatx4 acc[4][4];
#pragma unroll
  for (int i = 0; i < 4; ++i)
#pragma unroll
    for (int j = 0; j < 4; ++j) acc[i][j] = floatx4{0.f, 0.f, 0.f, 0.f};

  const int srow = tid >> 2;          // 0..63 (row within 64-row half)
  // pre-swizzled global column: chunk_slot (tid&3) gets global chunk
  // (tid&3) ^ f(row), f(row) = (row>>1)&3 = (tid>>3)&3
  const int scol = (((tid & 3) ^ ((tid >> 3) & 3))) * 8;
  const ushort* gA0 = A  + (size_t)(m0 + srow) * lda + scol;
  const ushort* gA1 = A  + (size_t)(m0 + 64 + srow) * lda + scol;
  const ushort* gB0 = Bw + (size_t)(n0 + srow) * K + scol;
  const ushort* gB1 = Bw + (size_t)(n0 + 64 + srow) * K + scol;

  STAGE(0, 0);
  STAGE(1, 32);
  int cur = 0;
  // read-side swizzle: per-lane constant granule XOR
  const int cs = (lhi ^ ((llo >> 1) & 3)) * 8;
  for (int kk = 0; kk < K; kk += 32) {
    if (kk + 64 < K) {
      int b2 = cur + 2; if (b2 >= 3) b2 -= 3;
      STAGE(b2, kk + 64);                         // keep 2 tiles in flight
      asm volatile("s_waitcnt vmcnt(8)" ::: "memory");  // tile kk landed
    } else if (kk + 32 < K) {
      asm volatile("s_waitcnt vmcnt(4)" ::: "memory");
    } else {
      asm volatile("s_waitcnt vmcnt(0)" ::: "memory");
    }
    __builtin_amdgcn_s_barrier();                 // all slices of buf[cur] landed
    __builtin_amdgcn_sched_barrier(0);

    const ushort* Ab = As + cur * 4096;
    const ushort* Bbp = Bs + cur * 4096;
    short8 af[4], bfr[4];
#pragma unroll
    for (int i = 0; i < 4; ++i) {
      af[i]  = *(const short8*)(Ab + (wr * 64 + i * 16 + llo) * 32 + cs);
      bfr[i] = *(const short8*)(Bbp + (wc * 64 + i * 16 + llo) * 32 + cs);
    }
#pragma unroll
    for (int i = 0; i < 4; ++i)
#pragma unroll
      for (int j = 0; j < 4; ++j)
        acc[i][j] = __builtin_amdgcn_mfma_f32_16x16x32_bf16(af[i], bfr[j], acc[i][j], 0, 0, 0);

    __builtin_amdgcn_sched_barrier(0);            // keep ds_reads in this phase
    __builtin_amdgcn_s_barrier();                 // reads done before buf reuse
    cur += 1; if (cur >= 3) cur -= 3;
  }

  float bv[4];
#pragma unroll
  for (int j = 0; j < 4; ++j) bv[j] = bias[n0 + wc * 64 + j * 16 + llo];

#pragma unroll
  for (int i = 0; i < 4; ++i) {
#pragma unroll
    for (int r2 = 0; r2 < 4; ++r2) {
      const int row = m0 + wr * 64 + i * 16 + lhi * 4 + r2;
      if (row >= m_valid) continue;
      const size_t rb = (size_t)row * N + n0 + wc * 64;
#pragma unroll
      for (int j = 0; j < 4; ++j) {
        float v = acc[i][j][r2] + bv[j];
        if (C_F32) ((float*)Cout)[rb + j * 16 + llo] = v;
        else       ((ushort*)Cout)[rb + j * 16 + llo] = f2b(v);
      }
    }
  }
}

// ---------------- V transpose pre-pass -------------------------------------
// C1 v-cols [b*Pp+p][h*64+ss]  ->  Vt[(b*Hh+h)*64+ss][p]  (p padded to 640, 0)
__global__ __launch_bounds__(256) void vtrans(const ushort* __restrict__ C1,
                                              ushort* __restrict__ Vt) {
  const int pt = blockIdx.x, h = blockIdx.y, b = blockIdx.z;
  __shared__ ushort Ts[64][72];
  const int t = threadIdx.x;
  const int rl = t >> 2, c16 = (t & 3) * 16;
  const int p = pt * 64 + rl;
  short8 a0 = {0,0,0,0,0,0,0,0}, a1 = {0,0,0,0,0,0,0,0};
  if (p < Pp) {
    const ushort* s = C1 + (size_t)(b * Pp + p) * 2304 + h * 64 + c16;
    a0 = *(const short8*)s;
    a1 = *(const short8*)(s + 8);
  }
  *(short8*)&Ts[rl][c16] = a0;
  *(short8*)&Ts[rl][c16 + 8] = a1;
  __syncthreads();
  const int ss = t >> 2, pc16 = (t & 3) * 16;
  short8 o0, o1;
#pragma unroll
  for (int i = 0; i < 8; ++i) {
    o0[i] = (short)Ts[pc16 + i][ss];
    o1[i] = (short)Ts[pc16 + 8 + i][ss];
  }
  ushort* d = Vt + ((size_t)(b * Hh + h) * 64 + ss) * PKV + pt * 64 + pc16;
  *(short8*)d = o0;
  *(short8*)(d + 8) = o1;
}

// ---------------- flash attention (no-max, deferred-sum) -------------------
// 128 q-rows/block (8 waves x 16 rows), T14 async-STAGE split.
// Q,K from C1 (q at +768, k at +1536); V from Vt (transposed, [bh*64+ss][p]).
// O written into C1 v-cols (stride 2304).
__global__ __launch_bounds__(512) void attn_fwd(
    ushort* C1, const ushort* __restrict__ Vt)
{
  const int qt = blockIdx.x, h = blockIdx.y, b = blockIdx.z;
  const int tid = threadIdx.x;
  const int lane = tid & 63, w = tid >> 6;          // w: 0..7
  const int llo = lane & 15, lhi = lane >> 4;

  __shared__ ushort Ks[64][72];      // K rows (kv-local x d), padded
  __shared__ ushort Vs[64][72];      // V^T rows (ss x kv-local), padded
  __shared__ ushort Ps[8][16][72];   // per-wave P tile (wave-private)

  const int q0 = qt * 128;
  const int qrow = q0 + w * 16 + llo;   // may exceed 576: finite, never stored
  const size_t qoff = (size_t)(b * Pp + qrow) * 2304 + 768 + h * 64;
  const short8 qf0 = *(const short8*)(C1 + qoff + lhi * 8);
  const short8 qf1 = *(const short8*)(C1 + qoff + 32 + lhi * 8);

  float ls[4] = {0.f, 0.f, 0.f, 0.f};
  floatx4 acc_o[4];
#pragma unroll
  for (int st = 0; st < 4; ++st) acc_o[st] = floatx4{0.f, 0.f, 0.f, 0.f};

  const int srow = tid >> 3;          // 0..63
  const int sc8 = (tid & 7) * 8;
  const ushort* kbase = C1 + (size_t)(b * Pp + srow) * 2304 + 1536 + h * 64 + sc8;
  const ushort* vbase = Vt + ((size_t)(b * Hh + h) * 64 + srow) * PKV + sc8;

  // T14 prologue: issue tile-0 loads
  short8 kc = *(const short8*)(kbase);
  short8 vc = *(const short8*)(vbase);

  for (int t = 0; t < 10; ++t) {
    __syncthreads();                  // prev iter LDS reads done
    *(short8*)&Ks[srow][sc8] = kc;
    *(short8*)&Vs[srow][sc8] = vc;
    if (t < 9) {                      // issue next tile loads; land during compute
      kc = *(const short8*)(kbase + (size_t)(t + 1) * 64 * 2304);
      vc = *(const short8*)(vbase + (t + 1) * 64);
    }
    __syncthreads();

    // S = Q K^T ; P = exp2(S*scale*log2e) (no max-sub: |S*scale| <~ 2)
    float pv[4][4];                   // [ntile][r]
#pragma unroll
    for (int ntl = 0; ntl < 4; ++ntl) {
      floatx4 acc = floatx4{0.f, 0.f, 0.f, 0.f};
      const short8 bf0 = *(const short8*)&Ks[ntl * 16 + llo][lhi * 8];
      const short8 bf1 = *(const short8*)&Ks[ntl * 16 + llo][32 + lhi * 8];
      acc = __builtin_amdgcn_mfma_f32_16x16x32_bf16(qf0, bf0, acc, 0, 0, 0);
      acc = __builtin_amdgcn_mfma_f32_16x16x32_bf16(qf1, bf1, acc, 0, 0, 0);
      const bool valid = (t * 64 + ntl * 16 + llo) < Pp;
#pragma unroll
      for (int r = 0; r < 4; ++r) {
        const float p = valid ? exp2f(acc[r] * SCALE_LOG2E) : 0.f;
        pv[ntl][r] = p;
        ls[r] += p;
      }
    }

    // P -> LDS (bf16), wave-private: no barrier needed
#pragma unroll
    for (int r = 0; r < 4; ++r)
#pragma unroll
      for (int ntl = 0; ntl < 4; ++ntl)
        Ps[w][lhi * 4 + r][ntl * 16 + llo] = f2b(pv[ntl][r]);

    // O += P V
    const short8 pa0 = *(const short8*)&Ps[w][llo][lhi * 8];
    const short8 pa1 = *(const short8*)&Ps[w][llo][32 + lhi * 8];
#pragma unroll
    for (int st = 0; st < 4; ++st) {
      const short8 vb0 = *(const short8*)&Vs[st * 16 + llo][lhi * 8];
      const short8 vb1 = *(const short8*)&Vs[st * 16 + llo][32 + lhi * 8];
      acc_o[st] = __builtin_amdgcn_mfma_f32_16x16x32_bf16(pa0, vb0, acc_o[st], 0, 0, 0);
      acc_o[st] = __builtin_amdgcn_mfma_f32_16x16x32_bf16(pa1, vb1, acc_o[st], 0, 0, 0);
    }
  }

  // single deferred sum-reduce across the 16 lanes holding each row
#pragma unroll
  for (int r = 0; r < 4; ++r) {
#pragma unroll
    for (int off = 1; off < 16; off <<= 1) ls[r] += __shfl_xor(ls[r], off, 64);
  }

#pragma unroll
  for (int r = 0; r < 4; ++r) {
    const int p = q0 + w * 16 + lhi * 4 + r;
    if (p < Pp) {
      const float inv = 1.f / ls[r];
      const size_t ob = (size_t)(b * Pp + p) * 2304 + h * 64;  // O into C1 v-cols
#pragma unroll
      for (int st = 0; st < 4; ++st)
        C1[ob + st * 16 + llo] = f2b(acc_o[st][r] * inv);
    }
  }
}

// ---------------- launch ----------------------------------------------------
extern "C" void kernel_launch(void* const* d_in, const int* in_sizes, int n_in,
                              void* d_out, int out_size, void* d_ws, size_t ws_size,
                              hipStream_t stream) {
  const float* x     = (const float*)d_in[0];
  const float* qkv_w = (const float*)d_in[1];
  const float* qkv_b = (const float*)d_in[2];
  const float* out_w = (const float*)d_in[3];
  const float* out_b = (const float*)d_in[4];
  float* out = (float*)d_out;

  char* ws = (char*)d_ws;
  // layout (118.75 MB total):
  //   Xb   [0, 28.51MB)            x bf16 (dead after QKV GEMM)
  //   W1b  [28.51, 32.05)          qkv_w bf16 (dead after QKV GEMM)
  //   C1b  [32.05, 117.57)         qkv out; O later overwrites its v-cols
  //   W3b  [117.57, 118.75)        out_w bf16 (live until final GEMM)
  //   Vtb  [0, 31.46)              overlays Xb+W1b (written after both die)
  ushort* Xb  = (ushort*)(ws);
  ushort* W1b = (ushort*)(ws + 28508160);
  ushort* C1b = (ushort*)(ws + 32047104);
  ushort* W3b = (ushort*)(ws + 117571584);
  ushort* Vtb = (ushort*)(ws);

  cvt_pad<<<2048, 256, 0, stream>>>(x, Xb, M_VALID * 768 / 4, M_PAD * 768 / 4);
  cvt_pad<<<1024, 256, 0, stream>>>(qkv_w, W1b, 2304 * 768 / 4, 2304 * 768 / 4);
  cvt_pad<<<512, 256, 0, stream>>>(out_w, W3b, 768 * 768 / 4, 768 * 768 / 4);

  gemm_bt<false><<<dim3(145 * 18), 256, 0, stream>>>(Xb, 768, W1b, qkv_b,
                                                     (void*)C1b, 2304, 768, M_PAD, 18);
  vtrans<<<dim3(10, 12, 32), 256, 0, stream>>>(C1b, Vtb);
  attn_fwd<<<dim3(5, 12, 32), 512, 0, stream>>>(C1b, Vtb);
  gemm_bt<true><<<dim3(145 * 6), 256, 0, stream>>>(C1b, 2304, W3b, out_b,
                                                   (void*)out, 768, 768, M_VALID, 6);
}

// Round 8
// 341.599 us; speedup vs baseline: 1.2211x; 1.0419x over previous
//
#include <hip/hip_runtime.h>
#include <stdint.h>

typedef __attribute__((ext_vector_type(8))) short short8;
typedef __attribute__((ext_vector_type(4))) float floatx4;

#define DEV static __device__ __forceinline__
#define AS1 __attribute__((address_space(1)))
#define AS3 __attribute__((address_space(3)))

constexpr int Bb = 32, Pp = 577, Dd = 768, Hh = 12;
constexpr int M_VALID = Bb * Pp;      // 18464
constexpr int M_PAD   = 18560;        // storage rows of C1/Xb
constexpr int PKV     = 640;          // padded kv length (10 * 64)
constexpr float SCALE_LOG2E = 0.10206207261596577f * 1.4426950408889634f;

DEV ushort f2b(float f) {
  union { float f; uint32_t u; } c; c.f = f;
  uint32_t u = c.u + 0x7fffu + ((c.u >> 16) & 1u);
  return (ushort)(u >> 16);
}

// ---------------- fp32 -> bf16 conversion with zero padding ----------------
__global__ void cvt_pad(const float* __restrict__ src, ushort* __restrict__ dst,
                        int n_valid4, int n_total4) {
  const float4* s4 = (const float4*)src;
  for (int i = blockIdx.x * blockDim.x + threadIdx.x; i < n_total4;
       i += gridDim.x * blockDim.x) {
    float4 v = make_float4(0.f, 0.f, 0.f, 0.f);
    if (i < n_valid4) v = s4[i];
    ushort4 o;
    o.x = f2b(v.x); o.y = f2b(v.y); o.z = f2b(v.z); o.w = f2b(v.w);
    ((ushort4*)dst)[i] = o;
  }
}

// ---------------- bf16 GEMM, 8-phase 256x256 schedule (T3+T4+T2+T5) -------
// C[M,N] = A[M,768] * B[N,768]^T + bias.  K=768 fixed (12 K-tiles of 64).
// 8 waves (2M x 4N), 512 threads; per-wave C = 128x64 (acc[8][4]).
// LDS 128KB: A,B each 2dbuf x 2Khalf x [256 rows][32 cols] (16KB regions).
// Phase: 12 ds_read_b128 -> lgkmcnt(0)+schedbar -> setprio(1) 32 MFMA
//        setprio(0) -> barrier -> stage 1 half-K-tile (4 gload_lds) into the
//        region just freed -> vmcnt(12) (3 half-tiles in flight) -> barrier.
// Granule-XOR swizzle (round-7-proven): slot(r,c) holds global granule
// c ^ ((r>>1)&3); staging pre-swizzles the global source column.
#define STAGEHALF(BUF, KH, STK)                                                \
  do {                                                                         \
    __builtin_amdgcn_global_load_lds(                                          \
        (const AS1 void*)(gAs + (STK) + (KH) * 32),                            \
        (AS3 void*)(As + (BUF) * 16384 + (KH) * 8192 + tid * 8), 16, 0, 0);    \
    __builtin_amdgcn_global_load_lds(                                          \
        (const AS1 void*)(gAs + (size_t)128 * lda + (STK) + (KH) * 32),        \
        (AS3 void*)(As + (BUF) * 16384 + (KH) * 8192 + 4096 + tid * 8), 16, 0, 0); \
    __builtin_amdgcn_global_load_lds(                                          \
        (const AS1 void*)(gBs + (STK) + (KH) * 32),                            \
        (AS3 void*)(Bs_ + (BUF) * 16384 + (KH) * 8192 + tid * 8), 16, 0, 0);   \
    __builtin_amdgcn_global_load_lds(                                          \
        (const AS1 void*)(gBs + (size_t)128 * 768 + (STK) + (KH) * 32),        \
        (AS3 void*)(Bs_ + (BUF) * 16384 + (KH) * 8192 + 4096 + tid * 8), 16, 0, 0); \
  } while (0)

#define PHASE(BUF, KH, STK)                                                    \
  do {                                                                         \
    const ushort* Ar = As + (BUF) * 16384 + (KH) * 8192;                       \
    const ushort* Br = Bs_ + (BUF) * 16384 + (KH) * 8192;                      \
    short8 af[8], bf[4];                                                       \
    _Pragma("unroll") for (int j = 0; j < 4; ++j)                              \
      bf[j] = *(const short8*)(Br + (wn * 64 + j * 16 + llo) * 32 + csw);      \
    _Pragma("unroll") for (int i = 0; i < 8; ++i)                              \
      af[i] = *(const short8*)(Ar + (wr * 128 + i * 16 + llo) * 32 + csw);     \
    asm volatile("s_waitcnt lgkmcnt(0)" ::: "memory");                         \
    __builtin_amdgcn_sched_barrier(0);                                         \
    __builtin_amdgcn_s_setprio(1);                                             \
    _Pragma("unroll") for (int i = 0; i < 8; ++i)                              \
      _Pragma("unroll") for (int j = 0; j < 4; ++j)                            \
        acc[i][j] = __builtin_amdgcn_mfma_f32_16x16x32_bf16(af[i], bf[j], acc[i][j], 0, 0, 0); \
    __builtin_amdgcn_s_setprio(0);                                             \
    __builtin_amdgcn_sched_barrier(0);                                         \
    __builtin_amdgcn_s_barrier();            /* all reads of region done */    \
    STAGEHALF(BUF, KH, STK);                 /* overwrite freed region   */    \
    asm volatile("s_waitcnt vmcnt(12)" ::: "memory");                          \
    __builtin_amdgcn_s_barrier();            /* 3-phase-old stage landed */    \
  } while (0)

template<bool C_F32>
__global__ __launch_bounds__(512, 2) void gemm8p(
    const ushort* __restrict__ A, int lda,
    const ushort* __restrict__ Bw,
    const float* __restrict__ bias, void* __restrict__ Cout,
    int N, int m_valid, int nt_n)
{
  __shared__ ushort As[32768];    // 64KB: 2buf x 2kh x 256 x 32
  __shared__ ushort Bs_[32768];   // 64KB
  const int tid = threadIdx.x;
  const int lane = tid & 63;
  const int w = tid >> 6;
  const int wr = w >> 2, wn = w & 3;     // 2 x 4 wave grid
  const int llo = lane & 15, lhi = lane >> 4;

  // bijective chunked XCD swizzle (m204)
  const int nwg = gridDim.x;
  const int L = blockIdx.x;
  const int q = nwg >> 3, r = nwg & 7;
  const int xcd = L & 7, pos = L >> 3;
  const int wgid = (xcd < r ? xcd * (q + 1) : r * (q + 1) + (xcd - r) * q) + pos;
  const int m0 = (wgid / nt_n) * 256, n0 = (wgid % nt_n) * 256;

  floatx4 acc[8][4];
#pragma unroll
  for (int i = 0; i < 8; ++i)
#pragma unroll
    for (int j = 0; j < 4; ++j) acc[i][j] = floatx4{0.f, 0.f, 0.f, 0.f};

  // staging source bases (pre-swizzled global column, coalescing preserved:
  // each 4-thread cluster covers one contiguous 64B half-row, permuted)
  const int sg = ((tid & 3) ^ ((tid >> 3) & 3)) * 8;
  const ushort* gAs = A  + (size_t)(m0 + (tid >> 2)) * lda + sg;
  const ushort* gBs = Bw + (size_t)(n0 + (tid >> 2)) * 768 + sg;
  // read-side granule XOR (per-lane constant)
  const int csw = (lhi ^ ((llo >> 1) & 3)) * 8;

  // prologue: stage tiles 0 and 1 fully (16 loads)
  STAGEHALF(0, 0, 0);
  STAGEHALF(0, 1, 0);
  STAGEHALF(1, 0, 64);
  STAGEHALF(1, 1, 64);
  asm volatile("s_waitcnt vmcnt(8)" ::: "memory");   // tile 0 landed
  __builtin_amdgcn_s_barrier();

  // main loop: 6 iterations x 4 phases (2 K-tiles each); 12 K-tiles total
#pragma unroll 1
  for (int m = 0; m < 6; ++m) {
    const int t2 = 2 * m + 2, t3 = 2 * m + 3;
    const int s0 = (t2 < 12 ? t2 : 11) * 64;
    const int s1 = (t3 < 12 ? t3 : 11) * 64;
    PHASE(0, 0, s0);
    PHASE(0, 1, s0);
    PHASE(1, 0, s1);
    PHASE(1, 1, s1);
  }

  float bv[4];
#pragma unroll
  for (int j = 0; j < 4; ++j) bv[j] = bias[n0 + wn * 64 + j * 16 + llo];

#pragma unroll
  for (int i = 0; i < 8; ++i) {
#pragma unroll
    for (int r2 = 0; r2 < 4; ++r2) {
      const int row = m0 + wr * 128 + i * 16 + lhi * 4 + r2;
      if (row >= m_valid) continue;
      const size_t rb = (size_t)row * N + n0 + wn * 64;
#pragma unroll
      for (int j = 0; j < 4; ++j) {
        float v = acc[i][j][r2] + bv[j];
        if (C_F32) ((float*)Cout)[rb + j * 16 + llo] = v;
        else       ((ushort*)Cout)[rb + j * 16 + llo] = f2b(v);
      }
    }
  }
}

// ---------------- V transpose pre-pass -------------------------------------
__global__ __launch_bounds__(256) void vtrans(const ushort* __restrict__ C1,
                                              ushort* __restrict__ Vt) {
  const int pt = blockIdx.x, h = blockIdx.y, b = blockIdx.z;
  __shared__ ushort Ts[64][72];
  const int t = threadIdx.x;
  const int rl = t >> 2, c16 = (t & 3) * 16;
  const int p = pt * 64 + rl;
  short8 a0 = {0,0,0,0,0,0,0,0}, a1 = {0,0,0,0,0,0,0,0};
  if (p < Pp) {
    const ushort* s = C1 + (size_t)(b * Pp + p) * 2304 + h * 64 + c16;
    a0 = *(const short8*)s;
    a1 = *(const short8*)(s + 8);
  }
  *(short8*)&Ts[rl][c16] = a0;
  *(short8*)&Ts[rl][c16 + 8] = a1;
  __syncthreads();
  const int ss = t >> 2, pc16 = (t & 3) * 16;
  short8 o0, o1;
#pragma unroll
  for (int i = 0; i < 8; ++i) {
    o0[i] = (short)Ts[pc16 + i][ss];
    o1[i] = (short)Ts[pc16 + 8 + i][ss];
  }
  ushort* d = Vt + ((size_t)(b * Hh + h) * 64 + ss) * PKV + pt * 64 + pc16;
  *(short8*)d = o0;
  *(short8*)(d + 8) = o1;
}

// ---------------- flash attention (no-max, deferred-sum) -------------------
__global__ __launch_bounds__(512) void attn_fwd(
    ushort* C1, const ushort* __restrict__ Vt)
{
  const int qt = blockIdx.x, h = blockIdx.y, b = blockIdx.z;
  const int tid = threadIdx.x;
  const int lane = tid & 63, w = tid >> 6;          // w: 0..7
  const int llo = lane & 15, lhi = lane >> 4;

  __shared__ ushort Ks[64][72];
  __shared__ ushort Vs[64][72];
  __shared__ ushort Ps[8][16][72];

  const int q0 = qt * 128;
  const int qrow = q0 + w * 16 + llo;
  const size_t qoff = (size_t)(b * Pp + qrow) * 2304 + 768 + h * 64;
  const short8 qf0 = *(const short8*)(C1 + qoff + lhi * 8);
  const short8 qf1 = *(const short8*)(C1 + qoff + 32 + lhi * 8);

  float ls[4] = {0.f, 0.f, 0.f, 0.f};
  floatx4 acc_o[4];
#pragma unroll
  for (int st = 0; st < 4; ++st) acc_o[st] = floatx4{0.f, 0.f, 0.f, 0.f};

  const int srow = tid >> 3;
  const int sc8 = (tid & 7) * 8;
  const ushort* kbase = C1 + (size_t)(b * Pp + srow) * 2304 + 1536 + h * 64 + sc8;
  const ushort* vbase = Vt + ((size_t)(b * Hh + h) * 64 + srow) * PKV + sc8;

  short8 kc = *(const short8*)(kbase);
  short8 vc = *(const short8*)(vbase);

  for (int t = 0; t < 10; ++t) {
    __syncthreads();
    *(short8*)&Ks[srow][sc8] = kc;
    *(short8*)&Vs[srow][sc8] = vc;
    if (t < 9) {
      kc = *(const short8*)(kbase + (size_t)(t + 1) * 64 * 2304);
      vc = *(const short8*)(vbase + (t + 1) * 64);
    }
    __syncthreads();

    float pv[4][4];
#pragma unroll
    for (int ntl = 0; ntl < 4; ++ntl) {
      floatx4 acc = floatx4{0.f, 0.f, 0.f, 0.f};
      const short8 bf0 = *(const short8*)&Ks[ntl * 16 + llo][lhi * 8];
      const short8 bf1 = *(const short8*)&Ks[ntl * 16 + llo][32 + lhi * 8];
      acc = __builtin_amdgcn_mfma_f32_16x16x32_bf16(qf0, bf0, acc, 0, 0, 0);
      acc = __builtin_amdgcn_mfma_f32_16x16x32_bf16(qf1, bf1, acc, 0, 0, 0);
      const bool valid = (t * 64 + ntl * 16 + llo) < Pp;
#pragma unroll
      for (int r = 0; r < 4; ++r) {
        const float p = valid ? exp2f(acc[r] * SCALE_LOG2E) : 0.f;
        pv[ntl][r] = p;
        ls[r] += p;
      }
    }

#pragma unroll
    for (int r = 0; r < 4; ++r)
#pragma unroll
      for (int ntl = 0; ntl < 4; ++ntl)
        Ps[w][lhi * 4 + r][ntl * 16 + llo] = f2b(pv[ntl][r]);

    const short8 pa0 = *(const short8*)&Ps[w][llo][lhi * 8];
    const short8 pa1 = *(const short8*)&Ps[w][llo][32 + lhi * 8];
#pragma unroll
    for (int st = 0; st < 4; ++st) {
      const short8 vb0 = *(const short8*)&Vs[st * 16 + llo][lhi * 8];
      const short8 vb1 = *(const short8*)&Vs[st * 16 + llo][32 + lhi * 8];
      acc_o[st] = __builtin_amdgcn_mfma_f32_16x16x32_bf16(pa0, vb0, acc_o[st], 0, 0, 0);
      acc_o[st] = __builtin_amdgcn_mfma_f32_16x16x32_bf16(pa1, vb1, acc_o[st], 0, 0, 0);
    }
  }

#pragma unroll
  for (int r = 0; r < 4; ++r) {
#pragma unroll
    for (int off = 1; off < 16; off <<= 1) ls[r] += __shfl_xor(ls[r], off, 64);
  }

#pragma unroll
  for (int r = 0; r < 4; ++r) {
    const int p = q0 + w * 16 + lhi * 4 + r;
    if (p < Pp) {
      const float inv = 1.f / ls[r];
      const size_t ob = (size_t)(b * Pp + p) * 2304 + h * 64;
#pragma unroll
      for (int st = 0; st < 4; ++st)
        C1[ob + st * 16 + llo] = f2b(acc_o[st][r] * inv);
    }
  }
}

// ---------------- launch ----------------------------------------------------
extern "C" void kernel_launch(void* const* d_in, const int* in_sizes, int n_in,
                              void* d_out, int out_size, void* d_ws, size_t ws_size,
                              hipStream_t stream) {
  const float* x     = (const float*)d_in[0];
  const float* qkv_w = (const float*)d_in[1];
  const float* qkv_b = (const float*)d_in[2];
  const float* out_w = (const float*)d_in[3];
  const float* out_b = (const float*)d_in[4];
  float* out = (float*)d_out;

  char* ws = (char*)d_ws;
  // layout (118.75 MB total). BM=256 OOB tail reads land in the NEXT buffer:
  //   Xb   [0, 28.51MB)   x bf16 (dead after QKV GEMM)
  //   W1b  [28.51, 32.05) qkv_w bf16 (dead after QKV GEMM)
  //   C1b  [32.05, 117.57) qkv out; O later overwrites its v-cols
  //   W3b  [117.57, 118.75) out_w bf16 (live until final GEMM)
  //   Vtb  [0, 31.46)     overlays Xb+W1b (written after both die)
  ushort* Xb  = (ushort*)(ws);
  ushort* W1b = (ushort*)(ws + 28508160);
  ushort* C1b = (ushort*)(ws + 32047104);
  ushort* W3b = (ushort*)(ws + 117571584);
  ushort* Vtb = (ushort*)(ws);

  cvt_pad<<<2048, 256, 0, stream>>>(x, Xb, M_VALID * 768 / 4, M_PAD * 768 / 4);
  cvt_pad<<<1024, 256, 0, stream>>>(qkv_w, W1b, 2304 * 768 / 4, 2304 * 768 / 4);
  cvt_pad<<<512, 256, 0, stream>>>(out_w, W3b, 768 * 768 / 4, 768 * 768 / 4);

  // M-tiles of 256: ceil(18560/256) = 73 (tail rows guarded by m_valid)
  gemm8p<false><<<dim3(73 * 9), 512, 0, stream>>>(Xb, 768, W1b, qkv_b,
                                                  (void*)C1b, 2304, M_PAD, 9);
  vtrans<<<dim3(10, 12, 32), 256, 0, stream>>>(C1b, Vtb);
  attn_fwd<<<dim3(5, 12, 32), 512, 0, stream>>>(C1b, Vtb);
  gemm8p<true><<<dim3(73 * 3), 512, 0, stream>>>(C1b, 2304, W3b, out_b,
                                                 (void*)out, 768, M_VALID, 3);
}